// Round 5
// baseline (116.156 us; speedup 1.0000x reference)
//
#include <hip/hip_runtime.h>

#define B_ROWS 1048576
#define K_CODES 16
#define D_DIM 64

constexpr int BLOCK = 256;
constexpr int GRID  = 2048;   // 32768 rows/iter, exactly 32 iters over B

// native clang vector type — accepted by __builtin_nontemporal_load/store
typedef float f32x4 __attribute__((ext_vector_type(4)));

// --- cross-lane helpers, ALL on the VALU (DPP), zero DS-pipe ops ---
// masks {1,2,7,15} span GF(2)^4 -> complete 16-lane butterfly without ds_swizzle.
__device__ __forceinline__ float xor1_dpp(float x) {   // quad_perm [1,0,3,2]
    return __builtin_bit_cast(float,
        __builtin_amdgcn_update_dpp(0, __builtin_bit_cast(int, x), 0xB1, 0xF, 0xF, true));
}
__device__ __forceinline__ float xor2_dpp(float x) {   // quad_perm [2,3,0,1]
    return __builtin_bit_cast(float,
        __builtin_amdgcn_update_dpp(0, __builtin_bit_cast(int, x), 0x4E, 0xF, 0xF, true));
}
__device__ __forceinline__ float xor7_dpp(float x) {   // row_half_mirror: lane ^= 7
    return __builtin_bit_cast(float,
        __builtin_amdgcn_update_dpp(0, __builtin_bit_cast(int, x), 0x141, 0xF, 0xF, true));
}
__device__ __forceinline__ float xor15_dpp(float x) {  // row_mirror: lane ^= 15
    return __builtin_bit_cast(float,
        __builtin_amdgcn_update_dpp(0, __builtin_bit_cast(int, x), 0x140, 0xF, 0xF, true));
}

// ---------------- Pass 1: indices + loss partials (read-dominated) ----------------
__global__ __launch_bounds__(BLOCK)
void vq_pass1(const float* __restrict__ z,
              const float* __restrict__ emb,
              float* __restrict__ out_idx,
              float* __restrict__ partials)
{
    __shared__ __align__(16) float s_emb[K_CODES * D_DIM];  // 4 KB
    __shared__ float s_se[K_CODES];
    __shared__ float s_w[BLOCK / 64];

    const int t = threadIdx.x;

    ((float4*)s_emb)[t] = ((const float4*)emb)[t];
    __syncthreads();

    // ||e_k||^2 per code, f32 sequential (identical rounding path to passing rounds)
    if (t < K_CODES) {
        float s = 0.f;
        #pragma unroll
        for (int c = 0; c < D_DIM; ++c) {
            float e = s_emb[t * D_DIM + c];
            s = fmaf(e, e, s);
        }
        s_se[t] = s;
    }
    __syncthreads();

    const int j = t & 15;
    // sigma relabeling (bijection) so the all-DPP stage order (15,7,2,1) reproduces
    // the passing rounds' dot tree bitwise. sigma(1)=8, sigma(2)=4, sigma(4)=14, sigma(8)=3.
    const int sj = ((j & 1) ? 8 : 0) ^ ((j & 2) ? 4 : 0)
                 ^ ((j & 4) ? 14 : 0) ^ ((j & 8) ? 3 : 0);

    float4 ereg[16];
    #pragma unroll
    for (int r = 0; r < 16; ++r)
        ereg[r] = *(const float4*)&s_emb[((r ^ j) * D_DIM) + sj * 4];
    const float se_j = s_se[j];

    float lossacc = 0.f;

    const int gid    = (blockIdx.x * BLOCK + t) >> 4;
    const int stride = (GRID * BLOCK) >> 4;             // 32768

    int row = gid;
    f32x4 zv = __builtin_nontemporal_load((const f32x4*)&z[(size_t)row * D_DIM + sj * 4]);

    while (row < B_ROWS) {
        const int nrow = row + stride;
        f32x4 zn = zv;
        if (nrow < B_ROWS)
            zn = __builtin_nontemporal_load((const f32x4*)&z[(size_t)nrow * D_DIM + sj * 4]);

        float p[16];
        #pragma unroll
        for (int r = 0; r < 16; ++r) {
            float4 e = ereg[r];
            p[r] = fmaf(zv.w, e.w, fmaf(zv.z, e.z, fmaf(zv.y, e.y, zv.x * e.x)));
        }

        float szp = fmaf(zv.w, zv.w, fmaf(zv.z, zv.z, fmaf(zv.y, zv.y, zv.x * zv.x)));
        szp += xor1_dpp(szp);
        szp += xor2_dpp(szp);
        szp += xor7_dpp(szp);
        szp += xor15_dpp(szp);

        #pragma unroll
        for (int r = 0; r < 8; ++r)  p[r] += xor15_dpp(p[15 - r]);
        #pragma unroll
        for (int r = 0; r < 4; ++r)  p[r] += xor7_dpp(p[7 - r]);
        p[0] += xor2_dpp(p[2]);
        p[1] += xor2_dpp(p[3]);
        p[0] += xor1_dpp(p[1]);
        const float dot = p[0];

        const float d = (szp + se_j) - 2.0f * dot;

        float vmin = d;
        vmin = fminf(vmin, xor1_dpp(vmin));
        vmin = fminf(vmin, xor2_dpp(vmin));
        vmin = fminf(vmin, xor7_dpp(vmin));
        vmin = fminf(vmin, xor15_dpp(vmin));
        unsigned long long bal = __ballot(d == vmin);
        unsigned int mask = (unsigned int)((bal >> (t & 48)) & 0xFFFFull);
        int kmin = __ffs(mask) - 1;

        // q chunk only feeds the loss accumulator here (latency-tolerant)
        const float4 qv = *(const float4*)&s_emb[kmin * D_DIM + sj * 4];
        float dx = zv.x - qv.x; lossacc = fmaf(dx, dx, lossacc);
        dx = zv.y - qv.y;       lossacc = fmaf(dx, dx, lossacc);
        dx = zv.z - qv.z;       lossacc = fmaf(dx, dx, lossacc);
        dx = zv.w - qv.w;       lossacc = fmaf(dx, dx, lossacc);

        if (j == 0) out_idx[row] = (float)kmin;

        zv  = zn;
        row = nrow;
    }

    lossacc += __shfl_xor(lossacc, 32, 64);
    lossacc += __shfl_xor(lossacc, 16, 64);
    lossacc += __shfl_xor(lossacc, 8, 64);
    lossacc += __shfl_xor(lossacc, 4, 64);
    lossacc += __shfl_xor(lossacc, 2, 64);
    lossacc += __shfl_xor(lossacc, 1, 64);
    if ((t & 63) == 0) s_w[t >> 6] = lossacc;
    __syncthreads();
    if (t == 0) partials[blockIdx.x] = (s_w[0] + s_w[1]) + (s_w[2] + s_w[3]);
}

// ---------------- Pass 2: q = emb[idx] broadcast (write-dominated) + loss finalize ----------------
__global__ __launch_bounds__(BLOCK)
void vq_pass2(const float* __restrict__ emb,
              const float* __restrict__ idxf,
              float* __restrict__ out_q,
              const float* __restrict__ partials,
              float* __restrict__ out_loss)
{
    __shared__ __align__(16) float s_emb[K_CODES * D_DIM];  // 4 KB
    __shared__ float sw[4];

    const int t = threadIdx.x;

    ((float4*)s_emb)[t] = ((const float4*)emb)[t];
    __syncthreads();

    // merged loss finalize (block 0 only; partials are ready — P1 completed)
    if (blockIdx.x == 0) {
        float s = 0.f;
        for (int i = t; i < GRID; i += 256) s += partials[i];
        s += __shfl_xor(s, 32, 64);
        s += __shfl_xor(s, 16, 64);
        s += __shfl_xor(s, 8, 64);
        s += __shfl_xor(s, 4, 64);
        s += __shfl_xor(s, 2, 64);
        s += __shfl_xor(s, 1, 64);
        if ((t & 63) == 0) sw[t >> 6] = s;
        __syncthreads();
        if (t == 0) {
            float tot = (sw[0] + sw[1]) + (sw[2] + sw[3]);
            // vq_loss = 1.25 * mean; 1.25 / 2^26 is exact in f32
            *out_loss = tot * (1.25f / (float)(B_ROWS * (size_t)D_DIM));
        }
    }

    const int j = t & 15;
    const int gid    = (blockIdx.x * BLOCK + t) >> 4;
    const int stride = (GRID * BLOCK) >> 4;             // 32768

    int row = gid;
    float kf = idxf[row];                 // 16 lanes same addr -> single request

    while (row < B_ROWS) {
        const int nrow = row + stride;
        float kn = kf;
        if (nrow < B_ROWS) kn = idxf[nrow];

        const int k = (int)kf;
        const f32x4 qv = *(const f32x4*)&s_emb[k * D_DIM + j * 4];
        __builtin_nontemporal_store(qv, (f32x4*)&out_q[(size_t)row * D_DIM + j * 4]);

        kf  = kn;
        row = nrow;
    }
}

extern "C" void kernel_launch(void* const* d_in, const int* in_sizes, int n_in,
                              void* d_out, int out_size, void* d_ws, size_t ws_size,
                              hipStream_t stream)
{
    const float* z   = (const float*)d_in[0];
    const float* emb = (const float*)d_in[1];
    float* out      = (float*)d_out;
    float* out_q    = out;                                  // [B,64]
    float* out_idx  = out + (size_t)B_ROWS * D_DIM;         // [B]
    float* out_loss = out_idx + B_ROWS;                     // [1]
    float* partials = (float*)d_ws;                         // GRID floats

    vq_pass1<<<GRID, BLOCK, 0, stream>>>(z, emb, out_idx, partials);
    vq_pass2<<<GRID, BLOCK, 0, stream>>>(emb, out_idx, out_q, partials, out_loss);
}

// Round 6
// 100.308 us; speedup vs baseline: 1.1580x; 1.1580x over previous
//
#include <hip/hip_runtime.h>

#define B_ROWS 1048576
#define K_CODES 16
#define D_DIM 64

constexpr int BLOCK = 256;
constexpr int GRID  = 2048;   // 32768 rows/iter, exactly 32 iters over B

// native clang vector type — accepted by __builtin_nontemporal_load/store
typedef float f32x4 __attribute__((ext_vector_type(4)));

// --- cross-lane helpers, ALL on the VALU (DPP), zero DS-pipe ops ---
// masks {1,2,7,15} span GF(2)^4 -> complete 16-lane butterfly without ds_swizzle.
__device__ __forceinline__ float xor1_dpp(float x) {   // quad_perm [1,0,3,2]
    return __builtin_bit_cast(float,
        __builtin_amdgcn_update_dpp(0, __builtin_bit_cast(int, x), 0xB1, 0xF, 0xF, true));
}
__device__ __forceinline__ float xor2_dpp(float x) {   // quad_perm [2,3,0,1]
    return __builtin_bit_cast(float,
        __builtin_amdgcn_update_dpp(0, __builtin_bit_cast(int, x), 0x4E, 0xF, 0xF, true));
}
__device__ __forceinline__ float xor7_dpp(float x) {   // row_half_mirror: lane ^= 7
    return __builtin_bit_cast(float,
        __builtin_amdgcn_update_dpp(0, __builtin_bit_cast(int, x), 0x141, 0xF, 0xF, true));
}
__device__ __forceinline__ float xor15_dpp(float x) {  // row_mirror: lane ^= 15
    return __builtin_bit_cast(float,
        __builtin_amdgcn_update_dpp(0, __builtin_bit_cast(int, x), 0x140, 0xF, 0xF, true));
}

// min-waves-per-EU = 4 -> VGPR cap 128 -> 16 waves/CU (in-flight bytes, Little's law)
__global__ __launch_bounds__(BLOCK, 4)
void vq_main(const float* __restrict__ z,
             const float* __restrict__ emb,
             float* __restrict__ out_q,
             float* __restrict__ out_idx,
             float* __restrict__ partials)
{
    __shared__ __align__(16) float s_emb[K_CODES * D_DIM];  // 4 KB
    __shared__ float s_se[K_CODES];
    __shared__ float s_w[BLOCK / 64];

    const int t = threadIdx.x;

    // stage embedding into LDS (1024 floats, 256 threads x float4)
    ((float4*)s_emb)[t] = ((const float4*)emb)[t];
    __syncthreads();

    // ||e_k||^2 per code, f32 sequential (identical rounding path to passing rounds)
    if (t < K_CODES) {
        float s = 0.f;
        #pragma unroll
        for (int c = 0; c < D_DIM; ++c) {
            float e = s_emb[t * D_DIM + c];
            s = fmaf(e, e, s);
        }
        s_se[t] = s;
    }
    __syncthreads();

    const int j = t & 15;
    // sigma relabeling (bijection) so the all-DPP stage order (15,7,2,1) reproduces
    // the passing rounds' dot tree bitwise. sigma(1)=8, sigma(2)=4, sigma(4)=14, sigma(8)=3.
    const int sj = ((j & 1) ? 8 : 0) ^ ((j & 2) ? 4 : 0)
                 ^ ((j & 4) ? 14 : 0) ^ ((j & 8) ? 3 : 0);

    // ereg[r] holds code (r ^ j)'s columns sj*4 .. sj*4+3 (select-free butterfly)
    float4 ereg[16];
    #pragma unroll
    for (int r = 0; r < 16; ++r)
        ereg[r] = *(const float4*)&s_emb[((r ^ j) * D_DIM) + sj * 4];
    const float se_j = s_se[j];

    float lossacc = 0.f;

    const int gid    = (blockIdx.x * BLOCK + t) >> 4;
    const int stride = (GRID * BLOCK) >> 4;             // 32768

    // 2-deep software prefetch: two independent loads in flight per wave
    int row = gid;
    f32x4 zv  = __builtin_nontemporal_load((const f32x4*)&z[(size_t)row * D_DIM + sj * 4]);
    f32x4 zn1 = zv;
    if (row + stride < B_ROWS)
        zn1 = __builtin_nontemporal_load((const f32x4*)&z[(size_t)(row + stride) * D_DIM + sj * 4]);

    while (row < B_ROWS) {
        const int prow = row + 2 * stride;
        f32x4 zn2 = zv;
        if (prow < B_ROWS)
            zn2 = __builtin_nontemporal_load((const f32x4*)&z[(size_t)prow * D_DIM + sj * 4]);

        // partial dots; p[r] = partial for code (r ^ j) over this lane's 4 columns
        float p[16];
        #pragma unroll
        for (int r = 0; r < 16; ++r) {
            float4 e = ereg[r];
            p[r] = fmaf(zv.w, e.w, fmaf(zv.z, e.z, fmaf(zv.y, e.y, zv.x * e.x)));
        }

        // ||z||^2 partial + 16-lane all-reduce (bitwise-identical tree to passing rounds)
        float szp = fmaf(zv.w, zv.w, fmaf(zv.z, zv.z, fmaf(zv.y, zv.y, zv.x * zv.x)));
        szp += xor1_dpp(szp);
        szp += xor2_dpp(szp);
        szp += xor7_dpp(szp);
        szp += xor15_dpp(szp);

        // select-free butterfly transpose-reduce, all-DPP, stage order (15,7,2,1)
        #pragma unroll
        for (int r = 0; r < 8; ++r)  p[r] += xor15_dpp(p[15 - r]);
        #pragma unroll
        for (int r = 0; r < 4; ++r)  p[r] += xor7_dpp(p[7 - r]);
        p[0] += xor2_dpp(p[2]);
        p[1] += xor2_dpp(p[3]);
        p[0] += xor1_dpp(p[1]);
        const float dot = p[0];

        // distance, f32-rounded exactly like ref: (||z||^2 + ||e_j||^2) - 2*dot
        const float d = (szp + se_j) - 2.0f * dot;

        // argmin over 16 lanes, first-occurrence tie-break (matches np.argmin)
        float vmin = d;
        vmin = fminf(vmin, xor1_dpp(vmin));
        vmin = fminf(vmin, xor2_dpp(vmin));
        vmin = fminf(vmin, xor7_dpp(vmin));
        vmin = fminf(vmin, xor15_dpp(vmin));
        unsigned long long bal = __ballot(d == vmin);
        unsigned int mask = (unsigned int)((bal >> (t & 48)) & 0xFFFFull);
        int kmin = __ffs(mask) - 1;

        // quantized chunk from LDS embedding (the only DS op in the loop)
        const float4 qv = *(const float4*)&s_emb[kmin * D_DIM + sj * 4];

        // loss partial
        float dx = zv.x - qv.x; lossacc = fmaf(dx, dx, lossacc);
        dx = zv.y - qv.y;       lossacc = fmaf(dx, dx, lossacc);
        dx = zv.z - qv.z;       lossacc = fmaf(dx, dx, lossacc);
        dx = zv.w - qv.w;       lossacc = fmaf(dx, dx, lossacc);

        f32x4 qn = { qv.x, qv.y, qv.z, qv.w };
        __builtin_nontemporal_store(qn, (f32x4*)&out_q[(size_t)row * D_DIM + sj * 4]);
        if (j == 0) out_idx[row] = (float)kmin;

        zv  = zn1;
        zn1 = zn2;
        row += stride;
    }

    // block loss reduction (deterministic)
    lossacc += __shfl_xor(lossacc, 32, 64);
    lossacc += __shfl_xor(lossacc, 16, 64);
    lossacc += __shfl_xor(lossacc, 8, 64);
    lossacc += __shfl_xor(lossacc, 4, 64);
    lossacc += __shfl_xor(lossacc, 2, 64);
    lossacc += __shfl_xor(lossacc, 1, 64);
    if ((t & 63) == 0) s_w[t >> 6] = lossacc;
    __syncthreads();
    if (t == 0) partials[blockIdx.x] = (s_w[0] + s_w[1]) + (s_w[2] + s_w[3]);
}

__global__ void vq_finalize(const float* __restrict__ partials, int n,
                            float* __restrict__ out_loss)
{
    __shared__ float sw[4];
    float s = 0.f;
    for (int i = threadIdx.x; i < n; i += 256) s += partials[i];
    s += __shfl_xor(s, 32, 64);
    s += __shfl_xor(s, 16, 64);
    s += __shfl_xor(s, 8, 64);
    s += __shfl_xor(s, 4, 64);
    s += __shfl_xor(s, 2, 64);
    s += __shfl_xor(s, 1, 64);
    if ((threadIdx.x & 63) == 0) sw[threadIdx.x >> 6] = s;
    __syncthreads();
    if (threadIdx.x == 0) {
        float tot = (sw[0] + sw[1]) + (sw[2] + sw[3]);
        // vq_loss = 1.25 * mean; 1.25 / 2^26 is exact in f32
        *out_loss = tot * (1.25f / (float)(B_ROWS * (size_t)D_DIM));
    }
}

extern "C" void kernel_launch(void* const* d_in, const int* in_sizes, int n_in,
                              void* d_out, int out_size, void* d_ws, size_t ws_size,
                              hipStream_t stream)
{
    const float* z   = (const float*)d_in[0];
    const float* emb = (const float*)d_in[1];
    float* out      = (float*)d_out;
    float* out_q    = out;                                  // [B,64]
    float* out_idx  = out + (size_t)B_ROWS * D_DIM;         // [B]
    float* out_loss = out_idx + B_ROWS;                     // [1]
    float* partials = (float*)d_ws;                         // GRID floats

    vq_main<<<GRID, BLOCK, 0, stream>>>(z, emb, out_q, out_idx, partials);
    vq_finalize<<<1, 256, 0, stream>>>(partials, GRID, out_loss);
}